// Round 3
// baseline (325.891 us; speedup 1.0000x reference)
//
#include <hip/hip_runtime.h>

// MSE-sum loss: out[0] = 0.5 * sum((a[i]-b[i])^2), n = 40e6 fp32 per input.
// R1/R2: persistent grid-stride stuck at ~2.7 TB/s effective regardless of
// per-wave MLP (unroll-4 neutral). R3: one-shot dispatch, block-contiguous
// 16 KB chunks (copy-benchmark-style sequential locality), two-stage
// reduction via d_ws (no atomic contention, no d_out memset launch).

__global__ __launch_bounds__(256) void mse_stage1(const float4* __restrict__ a4,
                                                  const float4* __restrict__ b4,
                                                  float* __restrict__ partial,
                                                  long n4) {
    const int t = threadIdx.x;
    const long base = (long)blockIdx.x * 1024;   // 1024 float4 = 16 KB per array per block
    const long i0 = base + t;
    const long i1 = base + 256 + t;
    const long i2 = base + 512 + t;
    const long i3 = base + 768 + t;

    float4 x0 = {0,0,0,0}, y0 = {0,0,0,0};
    float4 x1 = {0,0,0,0}, y1 = {0,0,0,0};
    float4 x2 = {0,0,0,0}, y2 = {0,0,0,0};
    float4 x3 = {0,0,0,0}, y3 = {0,0,0,0};

    // straight-line loads: 8 independent global_load_dwordx4 in flight
    if (i0 < n4) { x0 = a4[i0]; y0 = b4[i0]; }
    if (i1 < n4) { x1 = a4[i1]; y1 = b4[i1]; }
    if (i2 < n4) { x2 = a4[i2]; y2 = b4[i2]; }
    if (i3 < n4) { x3 = a4[i3]; y3 = b4[i3]; }

    float acc = 0.0f, d;
    d = x0.x - y0.x; acc += d * d;
    d = x0.y - y0.y; acc += d * d;
    d = x0.z - y0.z; acc += d * d;
    d = x0.w - y0.w; acc += d * d;
    d = x1.x - y1.x; acc += d * d;
    d = x1.y - y1.y; acc += d * d;
    d = x1.z - y1.z; acc += d * d;
    d = x1.w - y1.w; acc += d * d;
    d = x2.x - y2.x; acc += d * d;
    d = x2.y - y2.y; acc += d * d;
    d = x2.z - y2.z; acc += d * d;
    d = x2.w - y2.w; acc += d * d;
    d = x3.x - y3.x; acc += d * d;
    d = x3.y - y3.y; acc += d * d;
    d = x3.z - y3.z; acc += d * d;
    d = x3.w - y3.w; acc += d * d;

    // wave-64 shuffle reduction
    #pragma unroll
    for (int off = 32; off > 0; off >>= 1)
        acc += __shfl_down(acc, off, 64);

    __shared__ float wave_sums[4];
    const int lane = t & 63;
    const int wid  = t >> 6;
    if (lane == 0) wave_sums[wid] = acc;
    __syncthreads();

    if (t == 0)
        partial[blockIdx.x] = wave_sums[0] + wave_sums[1] + wave_sums[2] + wave_sums[3];
}

__global__ __launch_bounds__(256) void mse_stage2(const float* __restrict__ partial,
                                                  float* __restrict__ out,
                                                  int m) {
    float acc = 0.0f;
    for (int i = threadIdx.x; i < m; i += 256)
        acc += partial[i];

    #pragma unroll
    for (int off = 32; off > 0; off >>= 1)
        acc += __shfl_down(acc, off, 64);

    __shared__ float wave_sums[4];
    const int lane = threadIdx.x & 63;
    const int wid  = threadIdx.x >> 6;
    if (lane == 0) wave_sums[wid] = acc;
    __syncthreads();

    if (threadIdx.x == 0)
        out[0] = 0.5f * (wave_sums[0] + wave_sums[1] + wave_sums[2] + wave_sums[3]);
}

extern "C" void kernel_launch(void* const* d_in, const int* in_sizes, int n_in,
                              void* d_out, int out_size, void* d_ws, size_t ws_size,
                              hipStream_t stream) {
    const float4* a4 = (const float4*)d_in[0];
    const float4* b4 = (const float4*)d_in[1];
    float* out = (float*)d_out;
    float* partial = (float*)d_ws;

    const long n = (long)in_sizes[0];        // 40,000,000
    const long n4 = n >> 2;                  // 10,000,000 float4 groups (n % 4 == 0)
    const int blocks = (int)((n4 + 1023) / 1024);   // 9766 one-shot blocks

    mse_stage1<<<blocks, 256, 0, stream>>>(a4, b4, partial, n4);
    mse_stage2<<<1, 256, 0, stream>>>(partial, out, blocks);
}

// Round 5
// 296.693 us; speedup vs baseline: 1.0984x; 1.0984x over previous
//
#include <hip/hip_runtime.h>

// MSE-sum loss: out[0] = 0.5 * sum((a[i]-b[i])^2), n = 40e6 fp32 per input.
// R1-R3: three structurally different kernels (persistent, unrolled, one-shot
// contiguous) all plateau at ~2.9 TB/s effective / 18% HBM, nothing saturated.
// FETCH_SIZE == exactly one buffer: one stream L3-resident, one missing.
// R4/R5 theory: L3 miss-allocate/evict arbitration throttles the missing
// stream. Change: nontemporal loads (nt bit) -> misses stream w/o allocation.
// R5 fix: use native ext_vector_type for __builtin_nontemporal_load (the
// HIP_vector_type struct is rejected by the builtin).

typedef float fvec4 __attribute__((ext_vector_type(4)));

__global__ __launch_bounds__(256) void mse_stage1(const fvec4* __restrict__ a4,
                                                  const fvec4* __restrict__ b4,
                                                  float* __restrict__ partial,
                                                  long n4) {
    const int t = threadIdx.x;
    const long base = (long)blockIdx.x * 1024;   // 1024 float4 = 16 KB per array per block
    const long i0 = base + t;
    const long i1 = base + 256 + t;
    const long i2 = base + 512 + t;
    const long i3 = base + 768 + t;

    fvec4 x0 = {0,0,0,0}, y0 = {0,0,0,0};
    fvec4 x1 = {0,0,0,0}, y1 = {0,0,0,0};
    fvec4 x2 = {0,0,0,0}, y2 = {0,0,0,0};
    fvec4 x3 = {0,0,0,0}, y3 = {0,0,0,0};

    // straight-line nontemporal loads: 8 independent global_load_dwordx4 (nt)
    if (i0 < n4) { x0 = __builtin_nontemporal_load(&a4[i0]);
                   y0 = __builtin_nontemporal_load(&b4[i0]); }
    if (i1 < n4) { x1 = __builtin_nontemporal_load(&a4[i1]);
                   y1 = __builtin_nontemporal_load(&b4[i1]); }
    if (i2 < n4) { x2 = __builtin_nontemporal_load(&a4[i2]);
                   y2 = __builtin_nontemporal_load(&b4[i2]); }
    if (i3 < n4) { x3 = __builtin_nontemporal_load(&a4[i3]);
                   y3 = __builtin_nontemporal_load(&b4[i3]); }

    float acc = 0.0f, d;
    d = x0.x - y0.x; acc += d * d;
    d = x0.y - y0.y; acc += d * d;
    d = x0.z - y0.z; acc += d * d;
    d = x0.w - y0.w; acc += d * d;
    d = x1.x - y1.x; acc += d * d;
    d = x1.y - y1.y; acc += d * d;
    d = x1.z - y1.z; acc += d * d;
    d = x1.w - y1.w; acc += d * d;
    d = x2.x - y2.x; acc += d * d;
    d = x2.y - y2.y; acc += d * d;
    d = x2.z - y2.z; acc += d * d;
    d = x2.w - y2.w; acc += d * d;
    d = x3.x - y3.x; acc += d * d;
    d = x3.y - y3.y; acc += d * d;
    d = x3.z - y3.z; acc += d * d;
    d = x3.w - y3.w; acc += d * d;

    // wave-64 shuffle reduction
    #pragma unroll
    for (int off = 32; off > 0; off >>= 1)
        acc += __shfl_down(acc, off, 64);

    __shared__ float wave_sums[4];
    const int lane = t & 63;
    const int wid  = t >> 6;
    if (lane == 0) wave_sums[wid] = acc;
    __syncthreads();

    if (t == 0)
        partial[blockIdx.x] = wave_sums[0] + wave_sums[1] + wave_sums[2] + wave_sums[3];
}

__global__ __launch_bounds__(256) void mse_stage2(const float* __restrict__ partial,
                                                  float* __restrict__ out,
                                                  int m) {
    float acc = 0.0f;
    for (int i = threadIdx.x; i < m; i += 256)
        acc += partial[i];

    #pragma unroll
    for (int off = 32; off > 0; off >>= 1)
        acc += __shfl_down(acc, off, 64);

    __shared__ float wave_sums[4];
    const int lane = threadIdx.x & 63;
    const int wid  = threadIdx.x >> 6;
    if (lane == 0) wave_sums[wid] = acc;
    __syncthreads();

    if (threadIdx.x == 0)
        out[0] = 0.5f * (wave_sums[0] + wave_sums[1] + wave_sums[2] + wave_sums[3]);
}

extern "C" void kernel_launch(void* const* d_in, const int* in_sizes, int n_in,
                              void* d_out, int out_size, void* d_ws, size_t ws_size,
                              hipStream_t stream) {
    const fvec4* a4 = (const fvec4*)d_in[0];
    const fvec4* b4 = (const fvec4*)d_in[1];
    float* out = (float*)d_out;
    float* partial = (float*)d_ws;

    const long n = (long)in_sizes[0];        // 40,000,000
    const long n4 = n >> 2;                  // 10,000,000 float4 groups (n % 4 == 0)
    const int blocks = (int)((n4 + 1023) / 1024);   // 9766 one-shot blocks

    mse_stage1<<<blocks, 256, 0, stream>>>(a4, b4, partial, n4);
    mse_stage2<<<1, 256, 0, stream>>>(partial, out, blocks);
}